// Round 2
// baseline (138.833 us; speedup 1.0000x reference)
//
#include <hip/hip_runtime.h>
#include <stdint.h>

// Problem constants (fixed by reference)
#define N_IMG   16
#define C_IN    256
#define H_IN    32
#define W_IN    32
#define OH      30
#define OW      30
#define K_SEL   1152                  // C*KH*KW/2
#define OUTC    512
#define RY_TOT  (N_IMG * OH)          // 480 (n,y) rows
#define M_HAT   (RY_TOT * 32)         // 15360 = padded M (ow 30 -> 32)
#define X_ELEMS (N_IMG * C_IN * H_IN * W_IN)   // 4194304
#define OUT_SP  (OH * OW)             // 900
#define NSPLIT  2                     // split-K factor
#define KITERS  (K_SEL / 32 / NSPLIT) // 18 K-iters per split

typedef float f32x4  __attribute__((ext_vector_type(4)));
typedef short bf16x8 __attribute__((ext_vector_type(8)));   // 8 bf16 = 4 VGPRs

__device__ __forceinline__ unsigned short f2bf(float f) {   // fp32 -> bf16 RNE
    unsigned int u = __float_as_uint(f);
    u += 0x7FFFu + ((u >> 16) & 1u);
    return (unsigned short)(u >> 16);
}

// async global->LDS, 16B/lane. LDS dst is wave-uniform base; HW adds lane*16.
__device__ __forceinline__ void gl_lds16(const void* g, void* lds) {
    __builtin_amdgcn_global_load_lds(
        (const __attribute__((address_space(1))) unsigned int*)g,
        (__attribute__((address_space(3))) unsigned int*)lds,
        16, 0, 0);
}

// ---------------------------------------------------------------------------
// Prep: idx -> koff gather offsets AND weight (K_SEL x OUTC fp32) -> wT
// (OUTC x K_SEL bf16, k-contiguous). Grid covers 512*1152 exactly.
// ---------------------------------------------------------------------------
__global__ void prep_kernel(const int* __restrict__ idx, const float* __restrict__ w,
                            int* __restrict__ koff, unsigned short* __restrict__ wT) {
    int id = blockIdx.x * 256 + threadIdx.x;
    if (id < K_SEL) {
        int v   = idx[id];
        int c   = v / 9;
        int rem = v - c * 9;
        int i   = rem / 3;
        int j   = rem - i * 3;
        koff[id] = c * (H_IN * W_IN) + i * W_IN + j;
    }
    int o = id / K_SEL;
    int s = id - o * K_SEL;
    wT[id] = f2bf(w[s * OUTC + o]);                // writes coalesced; reads L2-resident
}

// ---------------------------------------------------------------------------
// Materialize bf16 im2col  Amat[m_hat][k], m_hat=(n*30+y)*32+xw
// Block = one ry (n,y) row x 128 k. LDS transpose: gather reads coalesced
// along xw, stores coalesced along k.
// ---------------------------------------------------------------------------
__global__ void amat_kernel(const float* __restrict__ x, const int* __restrict__ koff,
                            unsigned short* __restrict__ Am) {
    __shared__ float tile[32 * 129];               // [xw][k], +1 pad: conflict-free
    const int rb = blockIdx.x;                     // ry in [0,480)
    const int kb = blockIdx.y;                     // k-chunk in [0,9)
    const int t  = threadIdx.x;
    const int n  = rb / OH;
    const int y  = rb - n * OH;
    const int base = n * (C_IN * H_IN * W_IN) + y * W_IN;

    const int xw = t & 31;
    const int kq = t >> 5;                          // 0..7
#pragma unroll
    for (int r = 0; r < 16; ++r) {
        int kl = kq * 16 + r;                       // 0..127
        int g  = base + koff[kb * 128 + kl] + xw;   // lanes 0..31: 128B coalesced
        g = min(g, X_ELEMS - 1);                    // xw>=30 pad cols: clamp (ignored later)
        tile[xw * 129 + kl] = x[g];
    }
    __syncthreads();

    const int kp = t & 63;                          // k-pair 0..63
    const int xg = t >> 6;                          // 0..3
#pragma unroll
    for (int r = 0; r < 8; ++r) {
        int xw2 = r * 4 + xg;
        float f0 = tile[xw2 * 129 + 2 * kp];
        float f1 = tile[xw2 * 129 + 2 * kp + 1];
        unsigned int pk = (unsigned int)f2bf(f0) | ((unsigned int)f2bf(f1) << 16);
        size_t off = (size_t)(rb * 32 + xw2) * K_SEL + kb * 128 + 2 * kp;
        *reinterpret_cast<unsigned int*>(&Am[off]) = pk;   // 64 lanes x 4B contiguous
    }
}

// ---------------------------------------------------------------------------
// GEMM split-K=2: partial[sp][o][m_hat] = wT x Amat^T over K-half sp.
// 960 blocks (3.75/CU) vs 480 before — cross-block overlap hides the per-iter
// barrier drain that capped R1 (theory: 7.5 -> 15 waves/CU).
// Block 256 = 4 waves, tile 128(o) x 128(m), BK=32, 16x16x32 bf16 MFMA.
// ---------------------------------------------------------------------------
__global__ __launch_bounds__(256) void gemm_kernel(const unsigned short* __restrict__ wT,
                                                   const unsigned short* __restrict__ Am,
                                                   float* __restrict__ partial) {
    __shared__ __align__(16) unsigned short As[128 * 32];  // rows = o, k-contig
    __shared__ __align__(16) unsigned short Bs[128 * 32];  // rows = m_hat, k-contig

    const int t    = threadIdx.x;
    const int wave = t >> 6;
    const int lane = t & 63;
    const int quad = lane >> 4;
    const int lo   = lane & 15;

    const int bid = blockIdx.x;
    const int sp = bid & 1;                        // K-split
    const int ot = (bid >> 1) & 3;                 // 4 o-tiles
    const int mt = bid >> 3;                       // 120 m-tiles
    const int oBase = ot * 128;
    const int mBase = mt * 128;
    const int wo = (wave & 1) * 64;                // wave quadrant
    const int wm = (wave >> 1) * 64;

    f32x4 acc[4][4] = {};

    // staging coords: lane L -> row L/4 (of 16), k-sub (L%4)*8; LDS gets lane*16B
    const int lrow = lane >> 2;
    const int lks  = (lane & 3) * 8;
    const unsigned short* wrow0 = wT + (size_t)(oBase + wave * 16 + lrow) * K_SEL + lks;
    const unsigned short* wrow1 = wrow0 + (size_t)64 * K_SEL;
    const unsigned short* arow0 = Am + (size_t)(mBase + wave * 16 + lrow) * K_SEL + lks;
    const unsigned short* arow1 = arow0 + (size_t)64 * K_SEL;
    unsigned short* lA0 = &As[(wave * 16) * 32];
    unsigned short* lA1 = &As[(64 + wave * 16) * 32];
    unsigned short* lB0 = &Bs[(wave * 16) * 32];
    unsigned short* lB1 = &Bs[(64 + wave * 16) * 32];

    const int ktBeg = sp * KITERS;
    for (int kt = ktBeg; kt < ktBeg + KITERS; ++kt) {   // 18 iters per split
        const int k0 = kt * 32;
        gl_lds16(wrow0 + k0, lA0);
        gl_lds16(wrow1 + k0, lA1);
        gl_lds16(arow0 + k0, lB0);
        gl_lds16(arow1 + k0, lB1);
        __syncthreads();                           // drains vmcnt before barrier

        bf16x8 a[4], b[4];
#pragma unroll
        for (int ms = 0; ms < 4; ++ms)
            a[ms] = *(const bf16x8*)&As[(wo + ms * 16 + lo) * 32 + quad * 8];
#pragma unroll
        for (int ns = 0; ns < 4; ++ns)
            b[ns] = *(const bf16x8*)&Bs[(wm + ns * 16 + lo) * 32 + quad * 8];
#pragma unroll
        for (int ms = 0; ms < 4; ++ms)
#pragma unroll
            for (int ns = 0; ns < 4; ++ns)
                acc[ms][ns] = __builtin_amdgcn_mfma_f32_16x16x32_bf16(
                    a[ms], b[ns], acc[ms][ns], 0, 0, 0);
        __syncthreads();                           // LDS consumed before next stage
    }

    // Epilogue: plain coalesced stores to partial[sp][o][m_hat] (padded m kept).
    // D row = o (quad*4+reg), col = m_hat (lane&15): 16 lanes x 4B = 64B segments.
    float* pbase = partial + (size_t)sp * OUTC * M_HAT;
#pragma unroll
    for (int ns = 0; ns < 4; ++ns) {
        const int mh = mBase + wm + ns * 16 + lo;
#pragma unroll
        for (int ms = 0; ms < 4; ++ms) {
            const int o0 = oBase + wo + ms * 16 + quad * 4;
#pragma unroll
            for (int r = 0; r < 4; ++r)
                pbase[(size_t)(o0 + r) * M_HAT + mh] = acc[ms][ns][r];
        }
    }
}

// ---------------------------------------------------------------------------
// Combine: out[n,o,y,x] = p0[o][m_hat] + p1[o][m_hat]. Memory-bound (~92 MB).
// ---------------------------------------------------------------------------
__global__ void combine_kernel(const float* __restrict__ p, float* __restrict__ out) {
    int id = blockIdx.x * 256 + threadIdx.x;       // grid covers 16*512*900 exactly
    int n = id / (OUTC * OUT_SP);
    int r = id - n * (OUTC * OUT_SP);
    int o = r / OUT_SP;
    int s = r - o * OUT_SP;
    int y = s / OW;
    int xw = s - y * OW;
    size_t i0 = (size_t)o * M_HAT + (size_t)((n * OH + y) * 32 + xw);
    out[id] = p[i0] + p[(size_t)OUTC * M_HAT + i0];
}

// ---------------------------------------------------------------------------
extern "C" void kernel_launch(void* const* d_in, const int* in_sizes, int n_in,
                              void* d_out, int out_size, void* d_ws, size_t ws_size,
                              hipStream_t stream) {
    const float* x   = (const float*)d_in[0];
    const float* w   = (const float*)d_in[1];
    const int*   idx = (const int*)d_in[2];
    float*       out = (float*)d_out;

    // ws layout: koff 4608B | wT bf16 1179648B | Amat bf16 35389440B |
    //            partial fp32 2*512*15360*4 = 62914560B   (total ~99.5 MB)
    char* ws = (char*)d_ws;
    int*            koff = (int*)ws;
    unsigned short* wT   = (unsigned short*)(ws + 4608);
    unsigned short* Am   = (unsigned short*)(ws + 4608 + 1179648);
    float*          part = (float*)(ws + 4608 + 1179648 + 35389440);

    prep_kernel<<<dim3((OUTC * K_SEL) / 256), dim3(256), 0, stream>>>(idx, w, koff, wT);
    amat_kernel<<<dim3(RY_TOT, K_SEL / 128), dim3(256), 0, stream>>>(x, koff, Am);
    gemm_kernel<<<dim3((M_HAT / 128) * (OUTC / 128) * NSPLIT), dim3(256), 0, stream>>>(wT, Am, part);
    combine_kernel<<<dim3((N_IMG * OUTC * OUT_SP) / 256), dim3(256), 0, stream>>>(part, out);
}

// Round 3
// 113.455 us; speedup vs baseline: 1.2237x; 1.2237x over previous
//
#include <hip/hip_runtime.h>
#include <stdint.h>

// Problem constants (fixed by reference)
#define N_IMG   16
#define C_IN    256
#define H_IN    32
#define W_IN    32
#define OH      30
#define OW      30
#define K_SEL   1152                   // C*KH*KW/2
#define OUTC    512
#define RY_TOT  (N_IMG * OH)           // 480 (n,y) rows
#define M_HAT   (RY_TOT * 32)          // 15360 = padded M (ow 30 -> 32)
#define X_ELEMS (N_IMG * C_IN * H_IN * W_IN)   // 4194304
#define OUT_SP  (OH * OW)              // 900
#define CHW     (C_IN * H_IN * W_IN)   // 262144

#define TO      128                    // o-tile
#define TM      64                     // m-tile = 2 ry rows x 32 xw
#define NMT     (M_HAT / TM)           // 240
#define NOT     (OUTC / TO)            // 4
#define BSTR    40                     // Bs row stride (shorts): 80B rows -> 16B-aligned b128,
                                       // write conflicts capped at 4-way (m136: 1.58x)
#define KITER   (K_SEL / 32)           // 36

typedef float f32x4  __attribute__((ext_vector_type(4)));
typedef short bf16x8 __attribute__((ext_vector_type(8)));   // 8 bf16 = 4 VGPRs

__device__ __forceinline__ unsigned short f2bf(float f) {   // fp32 -> bf16 RNE
    unsigned int u = __float_as_uint(f);
    u += 0x7FFFu + ((u >> 16) & 1u);
    return (unsigned short)(u >> 16);
}

// async global->LDS, 16B/lane; LDS dst wave-uniform base, HW adds lane*16.
__device__ __forceinline__ void gl_lds16(const void* g, void* lds) {
    __builtin_amdgcn_global_load_lds(
        (const __attribute__((address_space(1))) unsigned int*)g,
        (__attribute__((address_space(3))) unsigned int*)lds,
        16, 0, 0);
}

// ---------------------------------------------------------------------------
// Prep: koff decode + coalesced LDS-tile transpose w(K_SEL x OUTC fp32) ->
// wT(OUTC x K_SEL bf16). Grid (36 s-tiles, 16 o-tiles) x 256 thr.
// ---------------------------------------------------------------------------
__global__ void prep_kernel(const int* __restrict__ idx, const float* __restrict__ w,
                            int* __restrict__ koff, unsigned short* __restrict__ wT) {
    __shared__ float tile[32][33];                 // +1 pad: phase1 conflict-free
    const int bx = blockIdx.x, by = blockIdx.y, t = threadIdx.x;

    if (by == 0) {                                 // fold koff decode into first row
        int k = bx * 256 + t;
        if (k < K_SEL) {
            int v = idx[k];
            int c = v / 9, rem = v - c * 9;
            int i = rem / 3, j = rem - i * 3;
            koff[k] = c * (H_IN * W_IN) + i * W_IN + j;
        }
    }
    const int s0 = bx * 32, o0 = by * 32;
    const int oc = t & 31, sg = t >> 5;
#pragma unroll
    for (int i = 0; i < 4; ++i) {                  // coalesced 128B reads along o
        int sl = sg * 4 + i;
        tile[sl][oc] = w[(s0 + sl) * OUTC + o0 + oc];
    }
    __syncthreads();
    const int ol = t >> 3, sq = t & 7;             // write along s: coalesced
    unsigned int u0 = (unsigned int)f2bf(tile[sq * 4 + 0][ol]) |
                      ((unsigned int)f2bf(tile[sq * 4 + 1][ol]) << 16);
    unsigned int u1 = (unsigned int)f2bf(tile[sq * 4 + 2][ol]) |
                      ((unsigned int)f2bf(tile[sq * 4 + 3][ol]) << 16);
    uint2 pk; pk.x = u0; pk.y = u1;
    *reinterpret_cast<uint2*>(&wT[(size_t)(o0 + ol) * K_SEL + s0 + sq * 4]) = pk;
}

// ---------------------------------------------------------------------------
// Fused GEMM: out[n,o,y,x] = sum_k wT[o][k] * x[n, koff[k] + y*32 + xw]
// Tile 128o x 64m (2 ry rows), BK=32, 960 blocks. B-tile staged straight from
// x (scalar gather -> bf16 pack -> ds_write_b64, k-contiguous rows); A-tile
// via global_load_lds (verified m97 path). x-gather software-pipelined 1 iter.
// ot = bid/240: o-siblings 240 apart -> same XCD (240%8==0) -> x L2 reuse.
// ---------------------------------------------------------------------------
__global__ __launch_bounds__(256, 4)
void gemm_kernel(const unsigned short* __restrict__ wT, const float* __restrict__ x,
                 const int* __restrict__ koff, float* __restrict__ out) {
    __shared__ __align__(16) unsigned short As[TO * 32];    // rows = o-local, k-contig
    __shared__ __align__(16) unsigned short Bs[TM * BSTR];  // rows = m-local, padded
    __shared__ int koS[K_SEL];

    const int t    = threadIdx.x;
    const int wave = t >> 6;
    const int lane = t & 63;
    const int quad = lane >> 4;
    const int lo   = lane & 15;

    const int bid = blockIdx.x;
    const int mt  = bid % NMT;
    const int ot  = bid / NMT;
    const int oBase = ot * TO;
    const int mBase = mt * TM;

    for (int i = t; i < K_SEL; i += 256) koS[i] = koff[i];

    int base[2];
#pragma unroll
    for (int ry = 0; ry < 2; ++ry) {
        int ryg = mt * 2 + ry;
        int n = ryg / 30, y = ryg - n * 30;
        base[ry] = n * CHW + y * W_IN;
    }

    const int xw  = t & 31;                        // spatial lane within ry row
    const int kq4 = t >> 5;                        // 0..7 -> 4 k's each
    const int ks  = kq4 * 4;

    // A staging: each wave owns 32 o-rows; 2 gl_lds16 of 1KB each.
    const int lrow = lane >> 2, lks = (lane & 3) * 8;
    const unsigned short* wrow0 = wT + (size_t)(oBase + wave * 32 + lrow) * K_SEL + lks;
    const unsigned short* wrow1 = wrow0 + (size_t)16 * K_SEL;
    unsigned short* lA0 = &As[(wave * 32) * 32];
    unsigned short* lA1 = lA0 + 16 * 32;

    __syncthreads();                               // koS ready

    f32x4 acc[2][4] = {};
    int   kk[2][4];
    float v[2][2][4];

    // prologue: prefetch x for kt=0
#pragma unroll
    for (int j = 0; j < 4; ++j) kk[0][j] = koS[ks + j];
#pragma unroll
    for (int ry = 0; ry < 2; ++ry)
#pragma unroll
        for (int j = 0; j < 4; ++j) {
            int g = base[ry] + kk[0][j] + xw;
            g = min(g, X_ELEMS - 1);               // xw>=30 garbage, masked at store
            v[0][ry][j] = x[g];
        }

#pragma unroll 2
    for (int kt = 0; kt < KITER; ++kt) {
        const int p = kt & 1, q = p ^ 1;
        const int k0 = kt * 32;
        gl_lds16(wrow0 + k0, lA0);
        gl_lds16(wrow1 + k0, lA1);
        // commit current B-tile: bf16 pack, k-contiguous ds_write_b64
#pragma unroll
        for (int ry = 0; ry < 2; ++ry) {
            unsigned int u0 = (unsigned int)f2bf(v[p][ry][0]) |
                              ((unsigned int)f2bf(v[p][ry][1]) << 16);
            unsigned int u1 = (unsigned int)f2bf(v[p][ry][2]) |
                              ((unsigned int)f2bf(v[p][ry][3]) << 16);
            uint2 pk; pk.x = u0; pk.y = u1;
            *reinterpret_cast<uint2*>(&Bs[(ry * 32 + xw) * BSTR + ks]) = pk;
        }
        // prefetch next iter's x (latency overlapped with MFMA below)
        if (kt + 1 < KITER) {
            const int k1 = k0 + 32;
#pragma unroll
            for (int j = 0; j < 4; ++j) kk[q][j] = koS[k1 + ks + j];
#pragma unroll
            for (int ry = 0; ry < 2; ++ry)
#pragma unroll
                for (int j = 0; j < 4; ++j) {
                    int g = base[ry] + kk[q][j] + xw;
                    g = min(g, X_ELEMS - 1);
                    v[q][ry][j] = x[g];
                }
        }
        __syncthreads();                           // As (vmcnt) + Bs (lgkmcnt) visible

        bf16x8 a[2], b[4];
#pragma unroll
        for (int ms = 0; ms < 2; ++ms)
            a[ms] = *(const bf16x8*)&As[(wave * 32 + ms * 16 + lo) * 32 + quad * 8];
#pragma unroll
        for (int ns = 0; ns < 4; ++ns)
            b[ns] = *(const bf16x8*)&Bs[(ns * 16 + lo) * BSTR + quad * 8];
#pragma unroll
        for (int ms = 0; ms < 2; ++ms)
#pragma unroll
            for (int ns = 0; ns < 4; ++ns)
                acc[ms][ns] = __builtin_amdgcn_mfma_f32_16x16x32_bf16(
                    a[ms], b[ns], acc[ms][ns], 0, 0, 0);
        __syncthreads();                           // tiles consumed before next stage
    }

    // Epilogue (verified R1 mapping): D row = o (quad*4+r), col = m (lane&15).
#pragma unroll
    for (int ns = 0; ns < 4; ++ns) {
        const int mh  = mBase + ns * 16 + lo;
        const int xwe = mh & 31;
        const int ryg = mh >> 5;
        const int n = ryg / 30, y = ryg - n * 30;
        if (xwe < OW) {
            const size_t ob = (size_t)n * (OUTC * OUT_SP) + (size_t)y * OW + xwe;
#pragma unroll
            for (int ms = 0; ms < 2; ++ms) {
                const int o0 = oBase + wave * 32 + ms * 16 + quad * 4;
#pragma unroll
                for (int r = 0; r < 4; ++r)
                    out[ob + (size_t)(o0 + r) * OUT_SP] = acc[ms][ns][r];
            }
        }
    }
}

// ---------------------------------------------------------------------------
extern "C" void kernel_launch(void* const* d_in, const int* in_sizes, int n_in,
                              void* d_out, int out_size, void* d_ws, size_t ws_size,
                              hipStream_t stream) {
    const float* x   = (const float*)d_in[0];
    const float* w   = (const float*)d_in[1];
    const int*   idx = (const int*)d_in[2];
    float*       out = (float*)d_out;

    // ws layout: koff 4608B | wT bf16 1179648B  (~1.2 MB total)
    char* ws = (char*)d_ws;
    int*            koff = (int*)ws;
    unsigned short* wT   = (unsigned short*)(ws + 4608);

    prep_kernel<<<dim3(K_SEL / 32, OUTC / 32), dim3(256), 0, stream>>>(idx, w, koff, wT);
    gemm_kernel<<<dim3(NMT * NOT), dim3(256), 0, stream>>>(wT, x, koff, out);
}